// Round 3
// baseline (264.768 us; speedup 1.0000x reference)
//
#include <hip/hip_runtime.h>
#include <hip/hip_bf16.h>
#include <stdint.h>

typedef __hip_bfloat16 bf16;
typedef __attribute__((ext_vector_type(8))) short s16x8;   // 8 bf16 (MFMA A/B frag)
typedef __attribute__((ext_vector_type(4))) float f32x4;   // MFMA C/D frag

__device__ __forceinline__ short f2bf_bits(float f) {
    union { bf16 b; short s; } u; u.b = __float2bfloat16(f); return u.s;
}

__device__ __forceinline__ void gload_lds16(const void* g, void* l) {
    __builtin_amdgcn_global_load_lds(
        (const __attribute__((address_space(1))) void*)(uintptr_t)g,
        (__attribute__((address_space(3))) void*)(uintptr_t)l,
        16, 0, 0);
}

__device__ __forceinline__ f32x4 mfma16(s16x8 a, s16x8 b, f32x4 c) {
    return __builtin_amdgcn_mfma_f32_16x16x32_bf16(a, b, c, 0, 0, 0);
}

// ---------------- convert x (fp32) -> bf16, vectorized 8/thread ----------------
__global__ __launch_bounds__(256) void cvt_bf16_kernel(const float* __restrict__ in,
                                                       bf16* __restrict__ out, int n8) {
    int i = blockIdx.x * blockDim.x + threadIdx.x;
    int stride = gridDim.x * blockDim.x;
    for (; i < n8; i += stride) {
        f32x4 a = ((const f32x4*)in)[2 * i];
        f32x4 b = ((const f32x4*)in)[2 * i + 1];
        s16x8 o;
        o[0] = f2bf_bits(a[0]); o[1] = f2bf_bits(a[1]);
        o[2] = f2bf_bits(a[2]); o[3] = f2bf_bits(a[3]);
        o[4] = f2bf_bits(b[0]); o[5] = f2bf_bits(b[1]);
        o[6] = f2bf_bits(b[2]); o[7] = f2bf_bits(b[3]);
        ((s16x8*)out)[i] = o;
    }
}

// ---------------- transpose + convert weights: out[C][R] = in[R][C] ----------------
__global__ __launch_bounds__(256) void transpose_cvt_kernel(const float* __restrict__ in,
                                                            bf16* __restrict__ out,
                                                            int R, int C) {
    __shared__ float t[32][33];
    int c0 = blockIdx.x * 32, r0 = blockIdx.y * 32;
    int lx = threadIdx.x & 31, ly = threadIdx.x >> 5;   // ly 0..7
    for (int i = ly; i < 32; i += 8)
        t[i][lx] = in[(size_t)(r0 + i) * C + (c0 + lx)];
    __syncthreads();
    for (int i = ly; i < 32; i += 8)
        out[(size_t)(c0 + i) * R + (r0 + lx)] = __float2bfloat16(t[lx][i]);
}

// ---------------- GEMM1: qkv = xb @ Wqkv_t^T + b; writes qT, kT (transposed), V ----------------
// A [32768][512] bf16, Bt [1536][512] bf16. Tile 128x128, BK=64, 4 waves.
__global__ __launch_bounds__(256, 2) void gemm_qkv_kernel(
    const bf16* __restrict__ A, const bf16* __restrict__ Bt,
    const float* __restrict__ bias,
    bf16* __restrict__ qT, bf16* __restrict__ kT, bf16* __restrict__ V) {
    __shared__ __align__(16) char smem[33280];           // max(As+Bs=32KB, tr=128*130*2)
    bf16* As = (bf16*)smem;                              // [128][64] swizzled
    bf16* Bs = (bf16*)(smem + 16384);
    const int tid = threadIdx.x;
    const int wid = tid >> 6, lane = tid & 63;
    const int r16 = lane & 15, rg = lane >> 4;
    const int wr = wid >> 1, wc = wid & 1;
    const int n0 = blockIdx.x * 128;
    const int m0 = blockIdx.y * 128;

    f32x4 acc[4][4] = {};
    for (int ks = 0; ks < 8; ++ks) {
        const int k0 = ks * 64;
#pragma unroll
        for (int it = 0; it < 4; ++it) {
            int f = (it * 256 + tid) << 4;               // byte in 16KB tile
            int row = f >> 7;
            int sc = ((f >> 4) & 7) ^ (row & 7);         // pre-swizzled source chunk
            gload_lds16((const char*)(A + (size_t)(m0 + row) * 512 + k0) + (sc << 4),
                        (char*)As + ((it * 256 + (wid << 6)) << 4));
            gload_lds16((const char*)(Bt + (size_t)(n0 + row) * 512 + k0) + (sc << 4),
                        (char*)Bs + ((it * 256 + (wid << 6)) << 4));
        }
        __syncthreads();
#pragma unroll
        for (int kk = 0; kk < 2; ++kk) {
            s16x8 af[4], bfv[4];
#pragma unroll
            for (int mi = 0; mi < 4; ++mi) {
                int row = (wr << 6) + (mi << 4) + r16;
                int off = (row << 7) + ((((kk << 2) + rg) ^ (row & 7)) << 4);
                af[mi] = *(const s16x8*)((const char*)As + off);
            }
#pragma unroll
            for (int ni = 0; ni < 4; ++ni) {
                int row = (wc << 6) + (ni << 4) + r16;
                int off = (row << 7) + ((((kk << 2) + rg) ^ (row & 7)) << 4);
                bfv[ni] = *(const s16x8*)((const char*)Bs + off);
            }
#pragma unroll
            for (int mi = 0; mi < 4; ++mi)
#pragma unroll
                for (int ni = 0; ni < 4; ++ni)
                    acc[mi][ni] = mfma16(af[mi], bfv[ni], acc[mi][ni]);
        }
        __syncthreads();
    }

    // epilogue: bias, (q) scale, route through LDS [128][130] for layout
    const int bb = m0 >> 12;        // batch
    const int l0 = m0 & 4095;       // l within batch
    const float scale = (n0 < 512) ? 0.015625f : 1.0f;   // L^-0.5 = 1/64 on q
    bf16* tr = (bf16*)smem;
    float bv[4];
#pragma unroll
    for (int ni = 0; ni < 4; ++ni)
        bv[ni] = bias[n0 + (wc << 6) + (ni << 4) + r16];
#pragma unroll
    for (int mi = 0; mi < 4; ++mi)
#pragma unroll
        for (int ni = 0; ni < 4; ++ni) {
            int col = (wc << 6) + (ni << 4) + r16;
#pragma unroll
            for (int r = 0; r < 4; ++r) {
                int row = (wr << 6) + (mi << 4) + (rg << 2) + r;
                tr[row * 130 + col] = __float2bfloat16((acc[mi][ni][r] + bv[ni]) * scale);
            }
        }
    __syncthreads();
    if (n0 < 1024) {                 // q or k block: transposed write qT[b][c][l]
        bf16* dst; int c0;
        if (n0 < 512) { dst = qT; c0 = n0; } else { dst = kT; c0 = n0 - 512; }
#pragma unroll 4
        for (int it = 0; it < 64; ++it) {
            int flat = it * 256 + tid;
            int cl = flat >> 7, ll = flat & 127;
            dst[((size_t)(bb * 512 + c0 + cl) << 12) + (l0 + ll)] = tr[ll * 130 + cl];
        }
    } else {                          // v block: normal layout V[m][c]
        int c0 = n0 - 1024;
#pragma unroll 4
        for (int it = 0; it < 64; ++it) {
            int flat = it * 256 + tid;
            int rr = flat >> 7, cc = flat & 127;
            V[((size_t)(m0 + rr) << 9) + (c0 + cc)] = tr[rr * 130 + cc];
        }
    }
}

// ---------------- S partial: S[d][e] += sum_l qT[d][l]*kT[e][l] over l-chunk ----------------
// grid (8 chunks, 64 bg); M=N=64, BK=64, wave tile 32x32.
__global__ __launch_bounds__(256, 2) void s_partial_kernel(
    const bf16* __restrict__ qT, const bf16* __restrict__ kT,
    float* __restrict__ S_part) {
    __shared__ __align__(16) bf16 qs[64 * 64];
    __shared__ __align__(16) bf16 ks2[64 * 64];
    const int chunk = blockIdx.x, bg = blockIdx.y;
    const int tid = threadIdx.x, wid = tid >> 6, lane = tid & 63;
    const int r16 = lane & 15, rg = lane >> 4;
    const int wr = wid >> 1, wc = wid & 1;
    const size_t base = ((size_t)bg << 18) + chunk * 512;   // (b*512+g*64)*4096 + chunk*512
    const bf16* qb = qT + base;
    const bf16* kb = kT + base;
    f32x4 acc[2][2] = {};
    for (int ks = 0; ks < 8; ++ks) {
#pragma unroll
        for (int it = 0; it < 2; ++it) {
            int f = (it * 256 + tid) << 4;
            int row = f >> 7;
            int sc = ((f >> 4) & 7) ^ (row & 7);
            gload_lds16((const char*)(qb + ((size_t)row << 12) + ks * 64) + (sc << 4),
                        (char*)qs + ((it * 256 + (wid << 6)) << 4));
            gload_lds16((const char*)(kb + ((size_t)row << 12) + ks * 64) + (sc << 4),
                        (char*)ks2 + ((it * 256 + (wid << 6)) << 4));
        }
        __syncthreads();
#pragma unroll
        for (int kk = 0; kk < 2; ++kk) {
            s16x8 aq[2], bk[2];
#pragma unroll
            for (int mi = 0; mi < 2; ++mi) {
                int row = (wr << 5) + (mi << 4) + r16;
                int off = (row << 7) + ((((kk << 2) + rg) ^ (row & 7)) << 4);
                aq[mi] = *(const s16x8*)((const char*)qs + off);
            }
#pragma unroll
            for (int ni = 0; ni < 2; ++ni) {
                int row = (wc << 5) + (ni << 4) + r16;
                int off = (row << 7) + ((((kk << 2) + rg) ^ (row & 7)) << 4);
                bk[ni] = *(const s16x8*)((const char*)ks2 + off);
            }
#pragma unroll
            for (int mi = 0; mi < 2; ++mi)
#pragma unroll
                for (int ni = 0; ni < 2; ++ni)
                    acc[mi][ni] = mfma16(aq[mi], bk[ni], acc[mi][ni]);
        }
        __syncthreads();
    }
    float* o = S_part + (((size_t)chunk << 6) + bg) * 4096;
#pragma unroll
    for (int mi = 0; mi < 2; ++mi)
#pragma unroll
        for (int ni = 0; ni < 2; ++ni)
#pragma unroll
            for (int r = 0; r < 4; ++r) {
                int row = (wr << 5) + (mi << 4) + (rg << 2) + r;
                int col = (wc << 5) + (ni << 4) + r16;
                o[(row << 6) + col] = acc[mi][ni][r];
            }
}

// ---------------- softmax over e: attn[bg][d][e] = softmax_e(sum_p S_part) ----------------
__global__ __launch_bounds__(256) void softmax_kernel(const float* __restrict__ S_part,
                                                      bf16* __restrict__ attn) {
    const int bg = blockIdx.x, tid = threadIdx.x;
    const int d = tid >> 2, q = tid & 3;
    const float* base = S_part + ((size_t)bg << 12) + (d << 6) + (q << 4);
    float s[16];
#pragma unroll
    for (int j = 0; j < 16; ++j) s[j] = 0.f;
    for (int p = 0; p < 8; ++p) {
        const float* pp = base + ((size_t)p << 18);
#pragma unroll
        for (int j = 0; j < 16; ++j) s[j] += pp[j];
    }
    float m = s[0];
#pragma unroll
    for (int j = 1; j < 16; ++j) m = fmaxf(m, s[j]);
    m = fmaxf(m, __shfl_xor(m, 1));
    m = fmaxf(m, __shfl_xor(m, 2));
    float sum = 0.f;
#pragma unroll
    for (int j = 0; j < 16; ++j) { s[j] = __expf(s[j] - m); sum += s[j]; }
    sum += __shfl_xor(sum, 1);
    sum += __shfl_xor(sum, 2);
    float inv = 1.0f / sum;
    bf16* o = attn + ((size_t)bg << 12) + (d << 6) + (q << 4);
#pragma unroll
    for (int j = 0; j < 16; ++j) o[j] = __float2bfloat16(s[j] * inv);
}

// ---------------- PV: out[l][d] = sum_e V[l][e] * attn[d][e] ----------------
// grid (16 l-chunks of 256, 64 bg); wave tile 64(l) x 64(d), K=64.
__global__ __launch_bounds__(256, 2) void pv_kernel(const bf16* __restrict__ V,
                                                    const bf16* __restrict__ attn,
                                                    bf16* __restrict__ aout) {
    const int lc = blockIdx.x, bg = blockIdx.y;
    const int b = bg >> 3, g = bg & 7;
    const int tid = threadIdx.x, wid = tid >> 6, lane = tid & 63;
    const int r16 = lane & 15, rg = lane >> 4;
    const bf16* ab = attn + ((size_t)bg << 12);
    s16x8 bfr[4][2];
#pragma unroll
    for (int ni = 0; ni < 4; ++ni)
#pragma unroll
        for (int kk = 0; kk < 2; ++kk)
            bfr[ni][kk] = *(const s16x8*)(ab + (((ni << 4) + r16) << 6) + (kk << 5) + (rg << 3));
    const size_t mrow = (size_t)b * 4096 + lc * 256 + wid * 64;
    const bf16* vb = V + (mrow << 9) + (g << 6);
    f32x4 acc[4][4] = {};
#pragma unroll
    for (int mi = 0; mi < 4; ++mi) {
#pragma unroll
        for (int kk = 0; kk < 2; ++kk) {
            s16x8 af = *(const s16x8*)(vb + (((size_t)(mi << 4) + r16) << 9) + (kk << 5) + (rg << 3));
#pragma unroll
            for (int ni = 0; ni < 4; ++ni)
                acc[mi][ni] = mfma16(af, bfr[ni][kk], acc[mi][ni]);
        }
    }
    bf16* ob = aout + (mrow << 9) + (g << 6);
#pragma unroll
    for (int mi = 0; mi < 4; ++mi)
#pragma unroll
        for (int ni = 0; ni < 4; ++ni)
#pragma unroll
            for (int r = 0; r < 4; ++r)
                ob[((size_t)((mi << 4) + (rg << 2) + r) << 9) + (ni << 4) + r16] =
                    __float2bfloat16(acc[mi][ni][r]);
}

// ---------------- proj GEMM: out = aout @ Wproj_t^T + b_proj (fp32 out) ----------------
__global__ __launch_bounds__(256, 2) void gemm_proj_kernel(
    const bf16* __restrict__ A, const bf16* __restrict__ Bt,
    const float* __restrict__ bias, float* __restrict__ out) {
    __shared__ __align__(16) char smem[32768];
    bf16* As = (bf16*)smem;
    bf16* Bs = (bf16*)(smem + 16384);
    const int tid = threadIdx.x;
    const int wid = tid >> 6, lane = tid & 63;
    const int r16 = lane & 15, rg = lane >> 4;
    const int wr = wid >> 1, wc = wid & 1;
    const int n0 = blockIdx.x * 128;
    const int m0 = blockIdx.y * 128;
    f32x4 acc[4][4] = {};
    for (int ks = 0; ks < 8; ++ks) {
        const int k0 = ks * 64;
#pragma unroll
        for (int it = 0; it < 4; ++it) {
            int f = (it * 256 + tid) << 4;
            int row = f >> 7;
            int sc = ((f >> 4) & 7) ^ (row & 7);
            gload_lds16((const char*)(A + (size_t)(m0 + row) * 512 + k0) + (sc << 4),
                        (char*)As + ((it * 256 + (wid << 6)) << 4));
            gload_lds16((const char*)(Bt + (size_t)(n0 + row) * 512 + k0) + (sc << 4),
                        (char*)Bs + ((it * 256 + (wid << 6)) << 4));
        }
        __syncthreads();
#pragma unroll
        for (int kk = 0; kk < 2; ++kk) {
            s16x8 af[4], bfv[4];
#pragma unroll
            for (int mi = 0; mi < 4; ++mi) {
                int row = (wr << 6) + (mi << 4) + r16;
                int off = (row << 7) + ((((kk << 2) + rg) ^ (row & 7)) << 4);
                af[mi] = *(const s16x8*)((const char*)As + off);
            }
#pragma unroll
            for (int ni = 0; ni < 4; ++ni) {
                int row = (wc << 6) + (ni << 4) + r16;
                int off = (row << 7) + ((((kk << 2) + rg) ^ (row & 7)) << 4);
                bfv[ni] = *(const s16x8*)((const char*)Bs + off);
            }
#pragma unroll
            for (int mi = 0; mi < 4; ++mi)
#pragma unroll
                for (int ni = 0; ni < 4; ++ni)
                    acc[mi][ni] = mfma16(af[mi], bfv[ni], acc[mi][ni]);
        }
        __syncthreads();
    }
    float bv[4];
#pragma unroll
    for (int ni = 0; ni < 4; ++ni)
        bv[ni] = bias[n0 + (wc << 6) + (ni << 4) + r16];
#pragma unroll
    for (int mi = 0; mi < 4; ++mi)
#pragma unroll
        for (int ni = 0; ni < 4; ++ni)
#pragma unroll
            for (int r = 0; r < 4; ++r)
                out[(size_t)(m0 + (wr << 6) + (mi << 4) + (rg << 2) + r) * 512 +
                    (n0 + (wc << 6) + (ni << 4) + r16)] = acc[mi][ni][r] + bv[ni];
}

// ---------------- tail: second tuple output = (float)size ----------------
__global__ void tail_kernel(const int* __restrict__ sz, float* __restrict__ out) {
    out[0] = (float)sz[0];
}

extern "C" void kernel_launch(void* const* d_in, const int* in_sizes, int n_in,
                              void* d_out, int out_size, void* d_ws, size_t ws_size,
                              hipStream_t stream) {
    const float* x      = (const float*)d_in[0];
    const float* W_qkv  = (const float*)d_in[1];
    const float* b_qkv  = (const float*)d_in[2];
    const float* W_proj = (const float*)d_in[3];
    const float* b_proj = (const float*)d_in[4];
    const int*   size_p = (const int*)d_in[5];
    float* out = (float*)d_out;

    char* ws = (char*)d_ws;
    bf16* xb      = (bf16*)ws;                    // 33,554,432 B
    bf16* Wqkv_t  = (bf16*)(ws + 33554432);       //  1,572,864
    bf16* Wproj_t = (bf16*)(ws + 35127296);       //    524,288
    bf16* qT      = (bf16*)(ws + 35651584);       // 33,554,432
    bf16* kT      = (bf16*)(ws + 69206016);       // 33,554,432
    bf16* V       = (bf16*)(ws + 102760448);      // 33,554,432 (ends 136,314,880)
    // aliases (lifetimes disjoint):
    float* S_part = (float*)xb;                   // 8 MB, after xb is dead
    bf16*  attn   = (bf16*)(ws + 8388608);        // 0.5 MB, inside dead xb region
    bf16*  aout   = qT;                           // qT dead after s_partial

    cvt_bf16_kernel<<<dim3(2048), dim3(256), 0, stream>>>(x, xb, 2097152);
    transpose_cvt_kernel<<<dim3(48, 16), dim3(256), 0, stream>>>(W_qkv, Wqkv_t, 512, 1536);
    transpose_cvt_kernel<<<dim3(16, 16), dim3(256), 0, stream>>>(W_proj, Wproj_t, 512, 512);
    gemm_qkv_kernel<<<dim3(12, 256), dim3(256), 0, stream>>>(xb, Wqkv_t, b_qkv, qT, kT, V);
    s_partial_kernel<<<dim3(8, 64), dim3(256), 0, stream>>>(qT, kT, S_part);
    softmax_kernel<<<dim3(64), dim3(256), 0, stream>>>(S_part, attn);
    pv_kernel<<<dim3(16, 64), dim3(256), 0, stream>>>(V, attn, aout);
    gemm_proj_kernel<<<dim3(4, 256), dim3(256), 0, stream>>>(aout, Wproj_t, b_proj, out);
    tail_kernel<<<1, 1, 0, stream>>>(size_p, out + (out_size - 1));
    (void)in_sizes; (void)n_in; (void)ws_size;
}

// Round 4
// 260.878 us; speedup vs baseline: 1.0149x; 1.0149x over previous
//
#include <hip/hip_runtime.h>
#include <hip/hip_bf16.h>
#include <stdint.h>

typedef __hip_bfloat16 bf16;
typedef __attribute__((ext_vector_type(8))) short s16x8;   // 8 bf16 (MFMA A/B frag)
typedef __attribute__((ext_vector_type(4))) short s16x4;   // 4 bf16
typedef __attribute__((ext_vector_type(4))) float f32x4;   // MFMA C/D frag

__device__ __forceinline__ short f2bf_bits(float f) {
    union { bf16 b; short s; } u; u.b = __float2bfloat16(f); return u.s;
}

__device__ __forceinline__ void gload_lds16(const void* g, void* l) {
    __builtin_amdgcn_global_load_lds(
        (const __attribute__((address_space(1))) void*)(uintptr_t)g,
        (__attribute__((address_space(3))) void*)(uintptr_t)l,
        16, 0, 0);
}

__device__ __forceinline__ f32x4 mfma16(s16x8 a, s16x8 b, f32x4 c) {
    return __builtin_amdgcn_mfma_f32_16x16x32_bf16(a, b, c, 0, 0, 0);
}

// ---------------- convert x (fp32) -> bf16, vectorized 8/thread ----------------
__global__ __launch_bounds__(256) void cvt_bf16_kernel(const float* __restrict__ in,
                                                       bf16* __restrict__ out, int n8) {
    int i = blockIdx.x * blockDim.x + threadIdx.x;
    int stride = gridDim.x * blockDim.x;
    for (; i < n8; i += stride) {
        f32x4 a = ((const f32x4*)in)[2 * i];
        f32x4 b = ((const f32x4*)in)[2 * i + 1];
        s16x8 o;
        o[0] = f2bf_bits(a[0]); o[1] = f2bf_bits(a[1]);
        o[2] = f2bf_bits(a[2]); o[3] = f2bf_bits(a[3]);
        o[4] = f2bf_bits(b[0]); o[5] = f2bf_bits(b[1]);
        o[6] = f2bf_bits(b[2]); o[7] = f2bf_bits(b[3]);
        ((s16x8*)out)[i] = o;
    }
}

// ---------------- transpose + convert weights: out[C][R] = in[R][C] ----------------
__global__ __launch_bounds__(256) void transpose_cvt_kernel(const float* __restrict__ in,
                                                            bf16* __restrict__ out,
                                                            int R, int C) {
    __shared__ float t[32][33];
    int c0 = blockIdx.x * 32, r0 = blockIdx.y * 32;
    int lx = threadIdx.x & 31, ly = threadIdx.x >> 5;   // ly 0..7
    for (int i = ly; i < 32; i += 8)
        t[i][lx] = in[(size_t)(r0 + i) * C + (c0 + lx)];
    __syncthreads();
    for (int i = ly; i < 32; i += 8)
        out[(size_t)(c0 + i) * R + (r0 + lx)] = __float2bfloat16(t[lx][i]);
}

// ---------------- GEMM1: qkv = xb @ Wqkv_t^T + b; writes qT, kT (transposed), V ----------------
// A [32768][512] bf16, Bt [1536][512] bf16. Tile 128x128, BK=64, 4 waves.
// T1: XCD-aware block swizzle (nwg=3072, 3072%8==0 -> simple bijective form).
__global__ __launch_bounds__(256, 2) void gemm_qkv_kernel(
    const bf16* __restrict__ A, const bf16* __restrict__ Bt,
    const float* __restrict__ bias,
    bf16* __restrict__ qT, bf16* __restrict__ kT, bf16* __restrict__ V) {
    __shared__ __align__(16) char smem[33280];           // max(As+Bs=32KB, tr=128*130*2)
    bf16* As = (bf16*)smem;                              // [128][64] swizzled
    bf16* Bs = (bf16*)(smem + 16384);
    const int tid = threadIdx.x;
    const int wid = tid >> 6, lane = tid & 63;
    const int r16 = lane & 15, rg = lane >> 4;
    const int wr = wid >> 1, wc = wid & 1;
    // XCD swizzle: dispatch order round-robins XCDs; give each XCD a contiguous
    // chunk of (m,n) tile space so A m-panels are reused within one L2.
    const int flat = blockIdx.y * 12 + blockIdx.x;       // 3072 tiles
    const int nb = (flat & 7) * 384 + (flat >> 3);
    const int n0 = (nb % 12) * 128;
    const int m0 = (nb / 12) * 128;

    f32x4 acc[4][4] = {};
    for (int ks = 0; ks < 8; ++ks) {
        const int k0 = ks * 64;
#pragma unroll
        for (int it = 0; it < 4; ++it) {
            int f = (it * 256 + tid) << 4;               // byte in 16KB tile
            int row = f >> 7;
            int sc = ((f >> 4) & 7) ^ (row & 7);         // pre-swizzled source chunk
            gload_lds16((const char*)(A + (size_t)(m0 + row) * 512 + k0) + (sc << 4),
                        (char*)As + ((it * 256 + (wid << 6)) << 4));
            gload_lds16((const char*)(Bt + (size_t)(n0 + row) * 512 + k0) + (sc << 4),
                        (char*)Bs + ((it * 256 + (wid << 6)) << 4));
        }
        __syncthreads();
#pragma unroll
        for (int kk = 0; kk < 2; ++kk) {
            s16x8 af[4], bfv[4];
#pragma unroll
            for (int mi = 0; mi < 4; ++mi) {
                int row = (wr << 6) + (mi << 4) + r16;
                int off = (row << 7) + ((((kk << 2) + rg) ^ (row & 7)) << 4);
                af[mi] = *(const s16x8*)((const char*)As + off);
            }
#pragma unroll
            for (int ni = 0; ni < 4; ++ni) {
                int row = (wc << 6) + (ni << 4) + r16;
                int off = (row << 7) + ((((kk << 2) + rg) ^ (row & 7)) << 4);
                bfv[ni] = *(const s16x8*)((const char*)Bs + off);
            }
#pragma unroll
            for (int mi = 0; mi < 4; ++mi)
#pragma unroll
                for (int ni = 0; ni < 4; ++ni)
                    acc[mi][ni] = mfma16(af[mi], bfv[ni], acc[mi][ni]);
        }
        __syncthreads();
    }

    // epilogue: bias, (q) scale, route through LDS [128][130] for layout
    const int bb = m0 >> 12;        // batch
    const int l0 = m0 & 4095;       // l within batch
    const float scale = (n0 < 512) ? 0.015625f : 1.0f;   // L^-0.5 = 1/64 on q
    bf16* tr = (bf16*)smem;
    float bv[4];
#pragma unroll
    for (int ni = 0; ni < 4; ++ni)
        bv[ni] = bias[n0 + (wc << 6) + (ni << 4) + r16];
#pragma unroll
    for (int mi = 0; mi < 4; ++mi)
#pragma unroll
        for (int ni = 0; ni < 4; ++ni) {
            int col = (wc << 6) + (ni << 4) + r16;
#pragma unroll
            for (int r = 0; r < 4; ++r) {
                int row = (wr << 6) + (mi << 4) + (rg << 2) + r;
                tr[row * 130 + col] = __float2bfloat16((acc[mi][ni][r] + bv[ni]) * scale);
            }
        }
    __syncthreads();
    if (n0 < 1024) {                 // q or k block: transposed write qT[b][c][l]
        bf16* dst; int c0;
        if (n0 < 512) { dst = qT; c0 = n0; } else { dst = kT; c0 = n0 - 512; }
#pragma unroll 4
        for (int it = 0; it < 64; ++it) {
            int flat2 = it * 256 + tid;
            int cl = flat2 >> 7, ll = flat2 & 127;
            dst[((size_t)(bb * 512 + c0 + cl) << 12) + (l0 + ll)] = tr[ll * 130 + cl];
        }
    } else {                          // v block: normal layout V[m][c]
        int c0 = n0 - 1024;
#pragma unroll 4
        for (int it = 0; it < 64; ++it) {
            int flat2 = it * 256 + tid;
            int rr = flat2 >> 7, cc = flat2 & 127;
            V[((size_t)(m0 + rr) << 9) + (c0 + cc)] = tr[rr * 130 + cc];
        }
    }
}

// ---------------- S partial: S[d][e] += sum_l qT[d][l]*kT[e][l] over l-chunk ----------------
// grid (16 chunks of 256 l, 64 bg); M=N=64, BK=64, wave tile 32x32.
__global__ __launch_bounds__(256, 2) void s_partial_kernel(
    const bf16* __restrict__ qT, const bf16* __restrict__ kT,
    float* __restrict__ S_part) {
    __shared__ __align__(16) bf16 qs[64 * 64];
    __shared__ __align__(16) bf16 ks2[64 * 64];
    const int chunk = blockIdx.x, bg = blockIdx.y;
    const int tid = threadIdx.x, wid = tid >> 6, lane = tid & 63;
    const int r16 = lane & 15, rg = lane >> 4;
    const int wr = wid >> 1, wc = wid & 1;
    const size_t base = ((size_t)bg << 18) + chunk * 256;   // (b*512+g*64)*4096 + chunk*256
    const bf16* qb = qT + base;
    const bf16* kb = kT + base;
    f32x4 acc[2][2] = {};
    for (int ks = 0; ks < 4; ++ks) {
#pragma unroll
        for (int it = 0; it < 2; ++it) {
            int f = (it * 256 + tid) << 4;
            int row = f >> 7;
            int sc = ((f >> 4) & 7) ^ (row & 7);
            gload_lds16((const char*)(qb + ((size_t)row << 12) + ks * 64) + (sc << 4),
                        (char*)qs + ((it * 256 + (wid << 6)) << 4));
            gload_lds16((const char*)(kb + ((size_t)row << 12) + ks * 64) + (sc << 4),
                        (char*)ks2 + ((it * 256 + (wid << 6)) << 4));
        }
        __syncthreads();
#pragma unroll
        for (int kk = 0; kk < 2; ++kk) {
            s16x8 aq[2], bk[2];
#pragma unroll
            for (int mi = 0; mi < 2; ++mi) {
                int row = (wr << 5) + (mi << 4) + r16;
                int off = (row << 7) + ((((kk << 2) + rg) ^ (row & 7)) << 4);
                aq[mi] = *(const s16x8*)((const char*)qs + off);
            }
#pragma unroll
            for (int ni = 0; ni < 2; ++ni) {
                int row = (wc << 5) + (ni << 4) + r16;
                int off = (row << 7) + ((((kk << 2) + rg) ^ (row & 7)) << 4);
                bk[ni] = *(const s16x8*)((const char*)ks2 + off);
            }
#pragma unroll
            for (int mi = 0; mi < 2; ++mi)
#pragma unroll
                for (int ni = 0; ni < 2; ++ni)
                    acc[mi][ni] = mfma16(aq[mi], bk[ni], acc[mi][ni]);
        }
        __syncthreads();
    }
    float* o = S_part + (((size_t)chunk << 6) + bg) * 4096;
#pragma unroll
    for (int mi = 0; mi < 2; ++mi)
#pragma unroll
        for (int ni = 0; ni < 2; ++ni)
#pragma unroll
            for (int r = 0; r < 4; ++r) {
                int row = (wr << 5) + (mi << 4) + (rg << 2) + r;
                int col = (wc << 5) + (ni << 4) + r16;
                o[(row << 6) + col] = acc[mi][ni][r];
            }
}

// ---------------- softmax over e: attn[bg][d][e] = softmax_e(sum_p S_part) ----------------
// grid (4 row-quarters, 64 bg), 256 threads: 16 rows/block, 16 lanes/row, 4 e's/lane.
__global__ __launch_bounds__(256) void softmax_kernel(const float* __restrict__ S_part,
                                                      bf16* __restrict__ attn) {
    const int q4 = blockIdx.x, bg = blockIdx.y;
    const int tid = threadIdx.x;
    const int dl = tid >> 4, es = tid & 15;
    const int d = (q4 << 4) + dl;
    const float* base = S_part + ((size_t)bg << 12) + (d << 6) + (es << 2);
    float s[4] = {0.f, 0.f, 0.f, 0.f};
#pragma unroll
    for (int p = 0; p < 16; ++p) {
        f32x4 v4 = *(const f32x4*)(base + ((size_t)p << 18));
        s[0] += v4[0]; s[1] += v4[1]; s[2] += v4[2]; s[3] += v4[3];
    }
    float m = fmaxf(fmaxf(s[0], s[1]), fmaxf(s[2], s[3]));
    m = fmaxf(m, __shfl_xor(m, 1));
    m = fmaxf(m, __shfl_xor(m, 2));
    m = fmaxf(m, __shfl_xor(m, 4));
    m = fmaxf(m, __shfl_xor(m, 8));
    float sum = 0.f;
#pragma unroll
    for (int j = 0; j < 4; ++j) { s[j] = __expf(s[j] - m); sum += s[j]; }
    sum += __shfl_xor(sum, 1);
    sum += __shfl_xor(sum, 2);
    sum += __shfl_xor(sum, 4);
    sum += __shfl_xor(sum, 8);
    float inv = 1.0f / sum;
    s16x4 w;
#pragma unroll
    for (int j = 0; j < 4; ++j) w[j] = f2bf_bits(s[j] * inv);
    *(s16x4*)(attn + ((size_t)bg << 12) + (d << 6) + (es << 2)) = w;
}

// ---------------- PV: out[l][d] = sum_e V[l][e] * attn[d][e] ----------------
// grid (16 l-chunks of 256, 64 bg); wave tile 64(l) x 64(d), K=64.
__global__ __launch_bounds__(256, 2) void pv_kernel(const bf16* __restrict__ V,
                                                    const bf16* __restrict__ attn,
                                                    bf16* __restrict__ aout) {
    const int lc = blockIdx.x, bg = blockIdx.y;
    const int b = bg >> 3, g = bg & 7;
    const int tid = threadIdx.x, wid = tid >> 6, lane = tid & 63;
    const int r16 = lane & 15, rg = lane >> 4;
    const bf16* ab = attn + ((size_t)bg << 12);
    s16x8 bfr[4][2];
#pragma unroll
    for (int ni = 0; ni < 4; ++ni)
#pragma unroll
        for (int kk = 0; kk < 2; ++kk)
            bfr[ni][kk] = *(const s16x8*)(ab + (((ni << 4) + r16) << 6) + (kk << 5) + (rg << 3));
    const size_t mrow = (size_t)b * 4096 + lc * 256 + wid * 64;
    const bf16* vb = V + (mrow << 9) + (g << 6);
    f32x4 acc[4][4] = {};
#pragma unroll
    for (int mi = 0; mi < 4; ++mi) {
#pragma unroll
        for (int kk = 0; kk < 2; ++kk) {
            s16x8 af = *(const s16x8*)(vb + (((size_t)(mi << 4) + r16) << 9) + (kk << 5) + (rg << 3));
#pragma unroll
            for (int ni = 0; ni < 4; ++ni)
                acc[mi][ni] = mfma16(af, bfr[ni][kk], acc[mi][ni]);
        }
    }
    bf16* ob = aout + (mrow << 9) + (g << 6);
#pragma unroll
    for (int mi = 0; mi < 4; ++mi)
#pragma unroll
        for (int ni = 0; ni < 4; ++ni)
#pragma unroll
            for (int r = 0; r < 4; ++r)
                ob[((size_t)((mi << 4) + (rg << 2) + r) << 9) + (ni << 4) + r16] =
                    __float2bfloat16(acc[mi][ni][r]);
}

// ---------------- proj GEMM: out = aout @ Wproj_t^T + b_proj (fp32 out) ----------------
// T1: XCD swizzle (nwg=1024, %8==0).
__global__ __launch_bounds__(256, 2) void gemm_proj_kernel(
    const bf16* __restrict__ A, const bf16* __restrict__ Bt,
    const float* __restrict__ bias, float* __restrict__ out) {
    __shared__ __align__(16) char smem[32768];
    bf16* As = (bf16*)smem;
    bf16* Bs = (bf16*)(smem + 16384);
    const int tid = threadIdx.x;
    const int wid = tid >> 6, lane = tid & 63;
    const int r16 = lane & 15, rg = lane >> 4;
    const int wr = wid >> 1, wc = wid & 1;
    const int flat = blockIdx.y * 4 + blockIdx.x;        // 1024 tiles
    const int nb = (flat & 7) * 128 + (flat >> 3);
    const int n0 = (nb & 3) * 128;
    const int m0 = (nb >> 2) * 128;
    f32x4 acc[4][4] = {};
    for (int ks = 0; ks < 8; ++ks) {
        const int k0 = ks * 64;
#pragma unroll
        for (int it = 0; it < 4; ++it) {
            int f = (it * 256 + tid) << 4;
            int row = f >> 7;
            int sc = ((f >> 4) & 7) ^ (row & 7);
            gload_lds16((const char*)(A + (size_t)(m0 + row) * 512 + k0) + (sc << 4),
                        (char*)As + ((it * 256 + (wid << 6)) << 4));
            gload_lds16((const char*)(Bt + (size_t)(n0 + row) * 512 + k0) + (sc << 4),
                        (char*)Bs + ((it * 256 + (wid << 6)) << 4));
        }
        __syncthreads();
#pragma unroll
        for (int kk = 0; kk < 2; ++kk) {
            s16x8 af[4], bfv[4];
#pragma unroll
            for (int mi = 0; mi < 4; ++mi) {
                int row = (wr << 6) + (mi << 4) + r16;
                int off = (row << 7) + ((((kk << 2) + rg) ^ (row & 7)) << 4);
                af[mi] = *(const s16x8*)((const char*)As + off);
            }
#pragma unroll
            for (int ni = 0; ni < 4; ++ni) {
                int row = (wc << 6) + (ni << 4) + r16;
                int off = (row << 7) + ((((kk << 2) + rg) ^ (row & 7)) << 4);
                bfv[ni] = *(const s16x8*)((const char*)Bs + off);
            }
#pragma unroll
            for (int mi = 0; mi < 4; ++mi)
#pragma unroll
                for (int ni = 0; ni < 4; ++ni)
                    acc[mi][ni] = mfma16(af[mi], bfv[ni], acc[mi][ni]);
        }
        __syncthreads();
    }
    float bv[4];
#pragma unroll
    for (int ni = 0; ni < 4; ++ni)
        bv[ni] = bias[n0 + (wc << 6) + (ni << 4) + r16];
#pragma unroll
    for (int mi = 0; mi < 4; ++mi)
#pragma unroll
        for (int ni = 0; ni < 4; ++ni)
#pragma unroll
            for (int r = 0; r < 4; ++r)
                out[(size_t)(m0 + (wr << 6) + (mi << 4) + (rg << 2) + r) * 512 +
                    (n0 + (wc << 6) + (ni << 4) + r16)] = acc[mi][ni][r] + bv[ni];
}

// ---------------- tail: second tuple output = (float)size ----------------
__global__ void tail_kernel(const int* __restrict__ sz, float* __restrict__ out) {
    out[0] = (float)sz[0];
}

extern "C" void kernel_launch(void* const* d_in, const int* in_sizes, int n_in,
                              void* d_out, int out_size, void* d_ws, size_t ws_size,
                              hipStream_t stream) {
    const float* x      = (const float*)d_in[0];
    const float* W_qkv  = (const float*)d_in[1];
    const float* b_qkv  = (const float*)d_in[2];
    const float* W_proj = (const float*)d_in[3];
    const float* b_proj = (const float*)d_in[4];
    const int*   size_p = (const int*)d_in[5];
    float* out = (float*)d_out;

    char* ws = (char*)d_ws;
    bf16* xb      = (bf16*)ws;                    // 33,554,432 B
    bf16* Wqkv_t  = (bf16*)(ws + 33554432);       //  1,572,864
    bf16* Wproj_t = (bf16*)(ws + 35127296);       //    524,288
    bf16* qT      = (bf16*)(ws + 35651584);       // 33,554,432
    bf16* kT      = (bf16*)(ws + 69206016);       // 33,554,432
    bf16* V       = (bf16*)(ws + 102760448);      // 33,554,432 (ends 136,314,880)
    // aliases (lifetimes disjoint):
    float* S_part = (float*)xb;                   // 16.8 MB (16 chunks), xb dead by then
    bf16*  attn   = (bf16*)(ws + 16777216);       // 0.5 MB, inside dead xb region
    bf16*  aout   = qT;                           // qT dead after s_partial

    cvt_bf16_kernel<<<dim3(2048), dim3(256), 0, stream>>>(x, xb, 2097152);
    transpose_cvt_kernel<<<dim3(48, 16), dim3(256), 0, stream>>>(W_qkv, Wqkv_t, 512, 1536);
    transpose_cvt_kernel<<<dim3(16, 16), dim3(256), 0, stream>>>(W_proj, Wproj_t, 512, 512);
    gemm_qkv_kernel<<<dim3(12, 256), dim3(256), 0, stream>>>(xb, Wqkv_t, b_qkv, qT, kT, V);
    s_partial_kernel<<<dim3(16, 64), dim3(256), 0, stream>>>(qT, kT, S_part);
    softmax_kernel<<<dim3(4, 64), dim3(256), 0, stream>>>(S_part, attn);
    pv_kernel<<<dim3(16, 64), dim3(256), 0, stream>>>(V, attn, aout);
    gemm_proj_kernel<<<dim3(4, 256), dim3(256), 0, stream>>>(aout, Wproj_t, b_proj, out);
    tail_kernel<<<1, 1, 0, stream>>>(size_p, out + (out_size - 1));
    (void)in_sizes; (void)n_in; (void)ws_size;
}